// Round 3
// baseline (488.456 us; speedup 1.0000x reference)
//
#include <hip/hip_runtime.h>
#include <hip/hip_bf16.h>
#include <stdint.h>

// QKV projection: C[M,N] = A[M,K] * W[N,K]^T + bias[N]
// M=16384, N=3072, K=1024, fp32 in/out, graded at bf16 tolerance.
// Stage 1: fused fp32->bf16 convert of A and W into d_ws (unchanged).
// Stage 2 (v4): PERSISTENT 256-block 256x256 bf16 GEMM, 3 output tiles per
// block. 8-phase / 2-K-tile pairs, reads one phase ahead, ONE barrier per
// phase (cohort lock), counted vmcnt(4) at phases 2/3/6/7 (never 0 in the
// main loop), T1 XCD swizzle, T2 3-bit LDS XOR swizzle, T5 setprio.
// Register plan (256-VGPR budget at 2 waves/SIMD): acc 128 + aA 32 + aB 32
// + bAe/bAo 16+16 + bB 16 = 240; only bA is double-buffered in regs (it is
// the only fragment consumed in the same phase its successor loads).
// Pair schedule (tiles e->buf0, o->buf1; stages tiles e+2,o+2):
//   ph1: rd bB(e)      |                      | Q00(aA,bAe) | lgkm0 bar
//   ph2: rd aB(e)      |                      | Q02(aA,bB)  | lgkm0 vm4 bar
//   ph3: rd bAo(o)     | stg B(e+2)->buf0.B   | Q40(aB,bAe) | lgkm0 vm4 bar
//   ph4: rd aA(o)      | stg A(e+2)->buf0.A   | Q42(aB,bB)  | lgkm0 bar
//   ph5: rd bB(o)      |                      | Q00(aA,bAo) | lgkm0 bar
//   ph6: rd aB(o)      |                      | Q02(aA,bB)  | lgkm0 vm4 bar
//   ph7: rd bAe(e+2)   | stg B(o+2)->buf1.B   | Q40(aB,bAo) | lgkm0 vm4 bar
//   ph8: rd aA(e+2)    | stg A(o+2)->buf1.A   | Q42(aB,bB)  | lgkm0 bar
// vm4 proof (issue order): at ph2-end outstanding = {ph7prev:4, ph8prev:4}
// -> drains ph7prev (buf1.B) needed by ph3's read; ph3-end drains ph8prev
// (buf1.A) for ph4; ph6-end drains ph3 (buf0.B) for ph7; ph7-end drains
// ph4 (buf0.A) for ph8. WAR: every staged region's last reader issued >=1
// {lgkm0,barrier} earlier. Round boundary: pair7 stages next round's tiles
// 0/1 and pre-reads their aA/bAe; epilogue stores overlap the next round's
// in-flight staging (stores are younger than the protected stages).

typedef __attribute__((ext_vector_type(8))) short short8;            // 8 x bf16
typedef __attribute__((ext_vector_type(8))) unsigned short ushort8;  // 8 x bf16 bits
typedef __attribute__((ext_vector_type(4))) float f32x4;

#define MTOT 16384
#define NTOT 3072
#define KTOT 1024
#define BUFS 65536     // one buffer: A region 32K + B region 32K
#define BREG 32768     // B region offset inside a buffer

#define WS_A_OFF   0u
#define WS_A_BYTES (MTOT * KTOT * 2u)
#define WS_W_OFF   (WS_A_OFF + WS_A_BYTES)

#define WAIT_LGKM0 asm volatile("s_waitcnt lgkmcnt(0)" ::: "memory")
#define WAIT_VM4   asm volatile("s_waitcnt vmcnt(4)" ::: "memory")
#define BARRIER    __builtin_amdgcn_s_barrier()

// ---- fused fp32->bf16 convert for A and W (unchanged) -------------------
__global__ __launch_bounds__(256) void cvt_aw(
    const float* __restrict__ A, const float* __restrict__ W,
    unsigned short* __restrict__ dA, unsigned short* __restrict__ dW)
{
    const float* src;
    unsigned short* dst;
    long i;
    if (blockIdx.x < 8192) {
        src = A; dst = dA;
        i = ((long)blockIdx.x * 256 + threadIdx.x) * 8;
    } else {
        src = W; dst = dW;
        i = ((long)(blockIdx.x - 8192) * 256 + threadIdx.x) * 8;
    }
    f32x4 a = *(const f32x4*)(src + i);
    f32x4 b = *(const f32x4*)(src + i + 4);
    ushort8 r;
    r[0] = __bfloat16_as_ushort(__float2bfloat16(a[0]));
    r[1] = __bfloat16_as_ushort(__float2bfloat16(a[1]));
    r[2] = __bfloat16_as_ushort(__float2bfloat16(a[2]));
    r[3] = __bfloat16_as_ushort(__float2bfloat16(a[3]));
    r[4] = __bfloat16_as_ushort(__float2bfloat16(b[0]));
    r[5] = __bfloat16_as_ushort(__float2bfloat16(b[1]));
    r[6] = __bfloat16_as_ushort(__float2bfloat16(b[2]));
    r[7] = __bfloat16_as_ushort(__float2bfloat16(b[3]));
    *(ushort8*)(dst + i) = r;
}

__device__ __forceinline__ void gload_lds16(const void* g, void* l) {
    __builtin_amdgcn_global_load_lds(
        (const __attribute__((address_space(1))) void*)g,
        (__attribute__((address_space(3))) void*)l,
        16, 0, 0);
}

// stage one 256x64 operand tile (4 x global_load_lds; wave w covers rows
// w*8..w*8+7 per quarter, source column pre-inverse-swizzled)
__device__ __forceinline__ void stage4(const unsigned short* g, char* l) {
    gload_lds16(g,          l);
    gload_lds16(g + 65536,  l + 8192);
    gload_lds16(g + 131072, l + 16384);
    gload_lds16(g + 196608, l + 24576);
}

// fragment loads (swizzled chunk addressing; ch0^64 = k-slice 1)
__device__ __forceinline__ void rd_a4(short8 (&d)[4][2], const char* base, int ch0) {
    const int c1 = ch0 ^ 64;
    #pragma unroll
    for (int i = 0; i < 4; ++i) {
        d[i][0] = *(const short8*)(base + i * 2048 + ch0);
        d[i][1] = *(const short8*)(base + i * 2048 + c1);
    }
}
__device__ __forceinline__ void rd_b2(short8 (&d)[2][2], const char* base, int ch0) {
    const int c1 = ch0 ^ 64;
    #pragma unroll
    for (int j = 0; j < 2; ++j) {
        d[j][0] = *(const short8*)(base + j * 2048 + ch0);
        d[j][1] = *(const short8*)(base + j * 2048 + c1);
    }
}

// one C-quadrant: 4(M) x 2(N) fragments x 2 k-slices = 16 MFMAs
template<int IO, int JO>
__device__ __forceinline__ void quad(f32x4 (&acc)[8][4],
                                     const short8 (&a)[4][2],
                                     const short8 (&b)[2][2])
{
    __builtin_amdgcn_s_setprio(1);
    #pragma unroll
    for (int i = 0; i < 4; ++i) {
        #pragma unroll
        for (int j = 0; j < 2; ++j) {
            f32x4 c = acc[IO + i][JO + j];
            c = __builtin_amdgcn_mfma_f32_16x16x32_bf16(a[i][0], b[j][0], c, 0, 0, 0);
            c = __builtin_amdgcn_mfma_f32_16x16x32_bf16(a[i][1], b[j][1], c, 0, 0, 0);
            acc[IO + i][JO + j] = c;
        }
    }
    __builtin_amdgcn_s_setprio(0);
}

// one pair of K-tiles (e -> buf0, o -> buf1); stages tiles e+2 (buf0) and
// o+2 (buf1) from the given global srcs when stg is set.
__device__ __forceinline__ void pair8(
    char* sm, int ra, int rb, int ch0, int w,
    const unsigned short* sAe, const unsigned short* sBe,
    const unsigned short* sAo, const unsigned short* sBo,
    bool stg,
    short8 (&aA)[4][2], short8 (&aB)[4][2],
    short8 (&bAe)[2][2], short8 (&bAo)[2][2], short8 (&bB)[2][2],
    f32x4 (&acc)[8][4])
{
    const char* A0 = sm + ra;          const char* B0 = sm + BREG + rb;
    const char* A1 = A0 + BUFS;        const char* B1 = B0 + BUFS;
    char* stA0 = sm + w * 1024;        char* stB0 = sm + BREG + w * 1024;
    char* stA1 = stA0 + BUFS;          char* stB1 = stB0 + BUFS;

    // ph1
    rd_b2(bB, B0 + 4096, ch0);
    quad<0, 0>(acc, aA, bAe);
    WAIT_LGKM0; BARRIER;
    // ph2
    rd_a4(aB, A0 + 8192, ch0);
    quad<0, 2>(acc, aA, bB);
    WAIT_LGKM0; WAIT_VM4; BARRIER;
    // ph3
    rd_b2(bAo, B1, ch0);
    if (stg) stage4(sBe, stB0);
    quad<4, 0>(acc, aB, bAe);
    WAIT_LGKM0; WAIT_VM4; BARRIER;
    // ph4
    rd_a4(aA, A1, ch0);
    if (stg) stage4(sAe, stA0);
    quad<4, 2>(acc, aB, bB);
    WAIT_LGKM0; BARRIER;
    // ph5
    rd_b2(bB, B1 + 4096, ch0);
    quad<0, 0>(acc, aA, bAo);
    WAIT_LGKM0; BARRIER;
    // ph6
    rd_a4(aB, A1 + 8192, ch0);
    quad<0, 2>(acc, aA, bB);
    WAIT_LGKM0; WAIT_VM4; BARRIER;
    // ph7
    rd_b2(bAe, B0, ch0);
    if (stg) stage4(sBo, stB1);
    quad<4, 0>(acc, aB, bAo);
    WAIT_LGKM0; WAIT_VM4; BARRIER;
    // ph8
    rd_a4(aA, A0, ch0);
    if (stg) stage4(sAo, stA1);
    quad<4, 2>(acc, aB, bB);
    WAIT_LGKM0; BARRIER;
}

__global__ __launch_bounds__(512, 2) void qkv_gemm_p(
    const unsigned short* __restrict__ A,   // [M,K] bf16 bits (ws)
    const unsigned short* __restrict__ W,   // [N,K] bf16 bits (ws)
    const float* __restrict__ bias,         // [N] f32
    float* __restrict__ C)                  // [M,N] f32
{
    __shared__ __align__(16) char sm[2 * BUFS];   // 128 KiB

    const int t    = threadIdx.x;
    const int l    = t & 63;
    const int w    = t >> 6;
    const int fr   = l & 15;
    const int qd   = l >> 4;
    const int bid  = blockIdx.x;

    const int wm = w >> 2, wn = w & 3;     // 2 M-warps x 4 N-warps
    const int wrow = wm * 128, wcol = wn * 64;

    // staging source: inverse-XOR-swizzled column (rule #21)
    const int srow = w * 8 + (l >> 3);
    const int schk = ((l & 7) ^ (l >> 3)) << 3;

    // LDS read addressing: phys chunk = logical chunk ^ (row&7)
    const int ra  = (wrow + fr) * 128;
    const int rb  = (wcol + fr) * 128;
    const int ch0 = (qd ^ (fr & 7)) << 4;

    f32x4 acc[8][4];
    short8 aA[4][2], aB[4][2], bAe[2][2], bAo[2][2], bB[2][2];

    // round r tile coords: same concurrent-set XCD layout as the 768-block
    // swizzle (virtual bid = r*256 + bid)
    int idx0 = (bid & 7) * 96 + (bid >> 3);
    int m0 = (idx0 / 12) * 256, n0 = (idx0 % 12) * 256;

    const unsigned short* gA = A + (size_t)(m0 + srow) * KTOT + schk;
    const unsigned short* gB = W + (size_t)(n0 + srow) * KTOT + schk;

    // prologue (round 0): stage t0->buf0, then B(t1), then A(t1) (issue
    // order matters for the counted vmcnt chain).
    {
        char* stA0 = sm + w * 1024;
        char* stB0 = sm + BREG + w * 1024;
        stage4(gA,      stA0);
        stage4(gB,      stB0);
        stage4(gB + 64, stB0 + BUFS);
        stage4(gA + 64, stA0 + BUFS);
        asm volatile("s_waitcnt vmcnt(8)" ::: "memory");  // t0 landed
        BARRIER;
        rd_b2(bAe, sm + BREG + rb, ch0);
        rd_a4(aA,  sm + ra,        ch0);
        WAIT_LGKM0;
    }

    #pragma unroll 1
    for (int r = 0; r < 3; ++r) {
        #pragma unroll
        for (int i = 0; i < 8; ++i)
            #pragma unroll
            for (int j = 0; j < 4; ++j)
                acc[i][j] = (f32x4){0.f, 0.f, 0.f, 0.f};

        const bool stg7 = (r < 2);
        const int rn = stg7 ? r + 1 : r;
        const int idxn = (bid & 7) * 96 + rn * 32 + (bid >> 3);
        const int m0n = (idxn / 12) * 256, n0n = (idxn % 12) * 256;
        const unsigned short* gA2 = A + (size_t)(m0n + srow) * KTOT + schk;
        const unsigned short* gB2 = W + (size_t)(n0n + srow) * KTOT + schk;

        #pragma unroll 1
        for (int p = 0; p < 7; ++p) {      // tiles 0..13, stage 2..15
            const int ke = (2 * p + 2) * 64, ko = (2 * p + 3) * 64;
            pair8(sm, ra, rb, ch0, w,
                  gA + ke, gB + ke, gA + ko, gB + ko, true,
                  aA, aB, bAe, bAo, bB, acc);
        }
        // tiles 14,15: stage next round's tiles 0,1 (or nothing, last round)
        pair8(sm, ra, rb, ch0, w,
              gA2, gB2, gA2 + 64, gB2 + 64, stg7,
              aA, aB, bAe, bAo, bB, acc);

        // epilogue: C/D layout col=lane&15, row=quad*4+reg (m89-verified)
        float bv[4];
        #pragma unroll
        for (int j = 0; j < 4; ++j)
            bv[j] = bias[n0 + wcol + j * 16 + fr];

        #pragma unroll
        for (int i = 0; i < 8; ++i) {
            const int row = m0 + wrow + i * 16 + qd * 4;
            #pragma unroll
            for (int j = 0; j < 4; ++j) {
                float* pp = C + (size_t)row * NTOT + (n0 + wcol + j * 16 + fr);
                #pragma unroll
                for (int rr = 0; rr < 4; ++rr)
                    pp[(size_t)rr * NTOT] = acc[i][j][rr] + bv[j];
            }
        }

        m0 = m0n; n0 = n0n; gA = gA2; gB = gB2;
    }
}

extern "C" void kernel_launch(void* const* d_in, const int* in_sizes, int n_in,
                              void* d_out, int out_size, void* d_ws, size_t ws_size,
                              hipStream_t stream) {
    const float* q  = (const float*)d_in[0];
    const float* Wq = (const float*)d_in[1];
    const float* bq = (const float*)d_in[2];
    float*       C  = (float*)d_out;

    char* ws = (char*)d_ws;
    unsigned short* wsA = (unsigned short*)(ws + WS_A_OFF);
    unsigned short* wsW = (unsigned short*)(ws + WS_W_OFF);

    cvt_aw<<<8192 + 1536, 256, 0, stream>>>(q, Wq, wsA, wsW);

    qkv_gemm_p<<<dim3(256), dim3(512), 0, stream>>>(wsA, wsW, bq, C);
}

// Round 4
// 342.147 us; speedup vs baseline: 1.4276x; 1.4276x over previous
//
#include <hip/hip_runtime.h>
#include <hip/hip_bf16.h>
#include <stdint.h>

// QKV projection: C[M,N] = A[M,K] * W[N,K]^T + bias[N]
// M=16384, N=3072, K=1024, fp32 in/out, graded at bf16 tolerance.
// Stage 1: fused fp32->bf16 convert of A and W into d_ws (unchanged).
// Stage 2 (v5): v3's verified 256x256 8-phase structure with the register
// plan fixed: SINGLE-COPY fragments (aA/aB/bA/bB = 96 VGPR, was 192).
// Liveness proof (per-tile schedule below): every fragment's next ds_read
// is >=1 sync-separated phase after its last MFMA use:
//   aA: used ph1,ph2 -> re-read ph3 (after ph2-end lgkm0+vm0+bar)
//   bA: used ph1,ph3 -> re-read ph4 (after ph3-end lgkm0+bar)
//   bB: used ph2,ph4 -> re-read next ph1 (compiler-tracked lgkm dep)
//   aB: used ph3,ph4 -> re-read next ph2
// Total ~250 VGPR incl. acc(128) -> fits 256 at 2 waves/SIMD, so regalloc
// keeps the one-phase-ahead reads hoisted (v3 needed ~320 and sank them;
// v4's plan spilled to scratch, poisoning the counted vmcnt waits).
// Per-tile schedule (tile t reads buf X=(t&1), stages t+2 into X):
//   ph1: rd bB(X.B+4096) | Q00(aA,bA)
//   ph2: rd aB(X.A+8192) | Q02(aA,bB) | lgkm0 vm0 bar
//   ph3: rd aA(Y)  | stg B(t+2)->X.B | Q40(aB,bA) | lgkm0 bar
//   ph4: rd bA(Y)  | stg A(t+2)->X.A | Q42(aB,bB)   (barrier-free into ph1)
// Race proof: X's last readers (ph1 bB, ph2 aB) are lgkm0'd+barrier'd at
// ph2-end before ph3/ph4 overwrite X; stages of tile t+1 (issued at t-1
// ph3/ph4, ~2000+ cyc old) are drained by this tile's ph2 vm0 before ph3
// reads buf Y. Prologue: per-wave vmcnt(8) BEFORE the barrier => all
// waves' tile-0 stages landed when any wave proceeds to the pre-reads.

typedef __attribute__((ext_vector_type(8))) short short8;            // 8 x bf16
typedef __attribute__((ext_vector_type(8))) unsigned short ushort8;  // 8 x bf16 bits
typedef __attribute__((ext_vector_type(4))) float f32x4;

#define MTOT 16384
#define NTOT 3072
#define KTOT 1024
#define BUFS 65536     // one buffer: A region 32K + B region 32K
#define BREG 32768     // B region offset inside a buffer

#define WS_A_OFF   0u
#define WS_A_BYTES (MTOT * KTOT * 2u)
#define WS_W_OFF   (WS_A_OFF + WS_A_BYTES)

#define WAIT_LGKM0 asm volatile("s_waitcnt lgkmcnt(0)" ::: "memory")
#define WAIT_VM0   asm volatile("s_waitcnt vmcnt(0)" ::: "memory")
#define BARRIER    __builtin_amdgcn_s_barrier()

// ---- fused fp32->bf16 convert for A and W (unchanged) -------------------
__global__ __launch_bounds__(256) void cvt_aw(
    const float* __restrict__ A, const float* __restrict__ W,
    unsigned short* __restrict__ dA, unsigned short* __restrict__ dW)
{
    const float* src;
    unsigned short* dst;
    long i;
    if (blockIdx.x < 8192) {
        src = A; dst = dA;
        i = ((long)blockIdx.x * 256 + threadIdx.x) * 8;
    } else {
        src = W; dst = dW;
        i = ((long)(blockIdx.x - 8192) * 256 + threadIdx.x) * 8;
    }
    f32x4 a = *(const f32x4*)(src + i);
    f32x4 b = *(const f32x4*)(src + i + 4);
    ushort8 r;
    r[0] = __bfloat16_as_ushort(__float2bfloat16(a[0]));
    r[1] = __bfloat16_as_ushort(__float2bfloat16(a[1]));
    r[2] = __bfloat16_as_ushort(__float2bfloat16(a[2]));
    r[3] = __bfloat16_as_ushort(__float2bfloat16(a[3]));
    r[4] = __bfloat16_as_ushort(__float2bfloat16(b[0]));
    r[5] = __bfloat16_as_ushort(__float2bfloat16(b[1]));
    r[6] = __bfloat16_as_ushort(__float2bfloat16(b[2]));
    r[7] = __bfloat16_as_ushort(__float2bfloat16(b[3]));
    *(ushort8*)(dst + i) = r;
}

__device__ __forceinline__ void gload_lds16(const void* g, void* l) {
    __builtin_amdgcn_global_load_lds(
        (const __attribute__((address_space(1))) void*)g,
        (__attribute__((address_space(3))) void*)l,
        16, 0, 0);
}

// stage one 256x64 operand tile (4 x global_load_lds; wave w writes rows
// w*8..w*8+7 of each 64-row quarter; source column pre-inverse-swizzled)
__device__ __forceinline__ void stage4(const unsigned short* g, char* l) {
    gload_lds16(g,          l);
    gload_lds16(g + 65536,  l + 8192);
    gload_lds16(g + 131072, l + 16384);
    gload_lds16(g + 196608, l + 24576);
}

// fragment loads (swizzled chunk addressing; ch0^64 = k-slice 1)
__device__ __forceinline__ void rd_a4(short8 (&d)[4][2], const char* base, int ch0) {
    const int c1 = ch0 ^ 64;
    #pragma unroll
    for (int i = 0; i < 4; ++i) {
        d[i][0] = *(const short8*)(base + i * 2048 + ch0);
        d[i][1] = *(const short8*)(base + i * 2048 + c1);
    }
}
__device__ __forceinline__ void rd_b2(short8 (&d)[2][2], const char* base, int ch0) {
    const int c1 = ch0 ^ 64;
    #pragma unroll
    for (int j = 0; j < 2; ++j) {
        d[j][0] = *(const short8*)(base + j * 2048 + ch0);
        d[j][1] = *(const short8*)(base + j * 2048 + c1);
    }
}

// one C-quadrant: 4(M) x 2(N) fragments x 2 k-slices = 16 MFMAs
template<int IO, int JO>
__device__ __forceinline__ void quad(f32x4 (&acc)[8][4],
                                     const short8 (&a)[4][2],
                                     const short8 (&b)[2][2])
{
    __builtin_amdgcn_s_setprio(1);
    #pragma unroll
    for (int i = 0; i < 4; ++i) {
        #pragma unroll
        for (int j = 0; j < 2; ++j) {
            f32x4 c = acc[IO + i][JO + j];
            c = __builtin_amdgcn_mfma_f32_16x16x32_bf16(a[i][0], b[j][0], c, 0, 0, 0);
            c = __builtin_amdgcn_mfma_f32_16x16x32_bf16(a[i][1], b[j][1], c, 0, 0, 0);
            acc[IO + i][JO + j] = c;
        }
    }
    __builtin_amdgcn_s_setprio(0);
}

// one K-tile; XOFF = this tile's buffer byte offset (compile-time).
// gAs/gBs = stage sources for tile t+2 (staged into THIS buffer).
template<int XOFF, bool STG>
__device__ __forceinline__ void ktile(
    char* sm, const unsigned short* gAs, const unsigned short* gBs,
    int ra, int rb, int ch0, int w,
    short8 (&aA)[4][2], short8 (&aB)[4][2],
    short8 (&bA)[2][2], short8 (&bB)[2][2],
    f32x4 (&acc)[8][4])
{
    constexpr int YOFF = XOFF ^ BUFS;
    const char* AX = sm + XOFF + ra;   const char* BX = sm + XOFF + BREG + rb;
    const char* AY = sm + YOFF + ra;   const char* BY = sm + YOFF + BREG + rb;
    char* stA = sm + XOFF + w * 1024;
    char* stB = sm + XOFF + BREG + w * 1024;

    // ph1: read bB (this tile's B rows 32..63) | Q00(aA,bA)
    rd_b2(bB, BX + 4096, ch0);
    quad<0, 0>(acc, aA, bA);

    // ph2: read aB (A rows 64..127) | Q02(aA,bB) | full drain + barrier
    rd_a4(aB, AX + 8192, ch0);
    quad<0, 2>(acc, aA, bB);
    WAIT_LGKM0; WAIT_VM0; BARRIER;

    // ph3: read next tile's aA (buf Y) | stage B(t+2)->X.B | Q40(aB,bA)
    rd_a4(aA, AY, ch0);
    if (STG) stage4(gBs, stB);
    quad<4, 0>(acc, aB, bA);
    WAIT_LGKM0; BARRIER;

    // ph4: read next tile's bA (buf Y) | stage A(t+2)->X.A | Q42(aB,bB)
    rd_b2(bA, BY, ch0);
    if (STG) stage4(gAs, stA);
    quad<4, 2>(acc, aB, bB);
    // barrier-free into next tile's ph1 (compiler tracks bA/bB lgkm deps)
}

__global__ __launch_bounds__(512, 2) void qkv_gemm_8ph(
    const unsigned short* __restrict__ A,   // [M,K] bf16 bits (ws)
    const unsigned short* __restrict__ W,   // [N,K] bf16 bits (ws)
    const float* __restrict__ bias,         // [N] f32
    float* __restrict__ C)                  // [M,N] f32
{
    __shared__ __align__(16) char sm[2 * BUFS];   // 128 KiB

    const int t    = threadIdx.x;
    const int l    = t & 63;
    const int w    = t >> 6;
    const int fr   = l & 15;
    const int qd   = l >> 4;

    // T1: XCD-bijective swizzle; 768 blocks = 8 XCDs x 96 (96 = 8 A-panels).
    const int bid = blockIdx.x;
    const int idx = (bid & 7) * 96 + (bid >> 3);
    const int mt = idx / 12, nt = idx % 12;
    const int m0 = mt * 256, n0 = nt * 256;

    const int wm = w >> 2, wn = w & 3;     // 2 M-warps x 4 N-warps
    const int wrow = wm * 128, wcol = wn * 64;

    // staging source: inverse-XOR-swizzled column (rule #21)
    const int srow = w * 8 + (l >> 3);
    const int schk = ((l & 7) ^ (l >> 3)) << 3;
    const unsigned short* gA = A + (size_t)(m0 + srow) * KTOT + schk;
    const unsigned short* gB = W + (size_t)(n0 + srow) * KTOT + schk;

    // LDS read addressing: phys chunk = logical chunk ^ (row&7)
    const int ra  = (wrow + fr) * 128;
    const int rb  = (wcol + fr) * 128;
    const int ch0 = (qd ^ (fr & 7)) << 4;

    f32x4 acc[8][4];
    #pragma unroll
    for (int i = 0; i < 8; ++i)
        #pragma unroll
        for (int j = 0; j < 4; ++j)
            acc[i][j] = (f32x4){0.f, 0.f, 0.f, 0.f};

    short8 aA[4][2], aB[4][2], bA[2][2], bB[2][2];

    // prologue: stage tile0 (A,B -> buf0) first, then tile1 (buf1).
    // vmcnt(8) drains exactly tile0's 8 stages; barrier AFTER it makes
    // that a block-wide guarantee; then pre-read tile0's aA,bA.
    {
        char* stA0 = sm + w * 1024;
        char* stB0 = sm + BREG + w * 1024;
        stage4(gA,      stA0);
        stage4(gB,      stB0);
        stage4(gB + 64, stB0 + BUFS);
        stage4(gA + 64, stA0 + BUFS);
        asm volatile("s_waitcnt vmcnt(8)" ::: "memory");
        BARRIER;
        rd_b2(bA, sm + BREG + rb, ch0);
        rd_a4(aA, sm + ra,        ch0);
        WAIT_LGKM0;
    }

    #pragma unroll 1
    for (int p = 0; p < 7; ++p) {          // tiles 0..13, staging tiles 2..15
        const int ke = (2 * p + 2) * 64;
        const int ko = (2 * p + 3) * 64;
        ktile<0,    true>(sm, gA + ke, gB + ke, ra, rb, ch0, w, aA, aB, bA, bB, acc);
        ktile<BUFS, true>(sm, gA + ko, gB + ko, ra, rb, ch0, w, aA, aB, bA, bB, acc);
    }
    // tiles 14,15: no staging (ph3/ph4 do harmless dead prefetches from LDS)
    ktile<0,    false>(sm, gA, gB, ra, rb, ch0, w, aA, aB, bA, bB, acc);
    ktile<BUFS, false>(sm, gA, gB, ra, rb, ch0, w, aA, aB, bA, bB, acc);

    // epilogue: C/D layout col=lane&15, row=quad*4+reg (m89-verified)
    float bv[4];
    #pragma unroll
    for (int j = 0; j < 4; ++j)
        bv[j] = bias[n0 + wcol + j * 16 + fr];

    #pragma unroll
    for (int i = 0; i < 8; ++i) {
        const int row = m0 + wrow + i * 16 + qd * 4;
        #pragma unroll
        for (int j = 0; j < 4; ++j) {
            float* pp = C + (size_t)row * NTOT + (n0 + wcol + j * 16 + fr);
            #pragma unroll
            for (int r = 0; r < 4; ++r)
                pp[(size_t)r * NTOT] = acc[i][j][r] + bv[j];
        }
    }
}

extern "C" void kernel_launch(void* const* d_in, const int* in_sizes, int n_in,
                              void* d_out, int out_size, void* d_ws, size_t ws_size,
                              hipStream_t stream) {
    const float* q  = (const float*)d_in[0];
    const float* Wq = (const float*)d_in[1];
    const float* bq = (const float*)d_in[2];
    float*       C  = (float*)d_out;

    char* ws = (char*)d_ws;
    unsigned short* wsA = (unsigned short*)(ws + WS_A_OFF);
    unsigned short* wsW = (unsigned short*)(ws + WS_W_OFF);

    cvt_aw<<<8192 + 1536, 256, 0, stream>>>(q, Wq, wsA, wsW);

    qkv_gemm_8ph<<<dim3(768), dim3(512), 0, stream>>>(wsA, wsW, bq, C);
}